// Round 5
// baseline (340.569 us; speedup 1.0000x reference)
//
#include <hip/hip_runtime.h>
#include <hip/hip_bf16.h>

typedef unsigned short u16;
typedef __attribute__((ext_vector_type(8))) short bf16x8;
typedef __attribute__((ext_vector_type(4))) float f32x4;
typedef __attribute__((ext_vector_type(4))) unsigned short u16x4;
typedef __attribute__((ext_vector_type(8))) unsigned short u16x8;

#define BATCH 4096
#define INF   1024
#define NH    4096   // 64 leaves * 64 hidden
#define OUTF  512
#define NLEAF 64
#define FDEPTH 6
#define ZSPL  8      // GEMM2 split-K ways

// Scratch as device globals (fully rewritten every call; no ws_size dependency).
__device__ __align__(16) u16  g_Xb[(size_t)BATCH * INF];     // x, bf16 (b,k)
__device__ __align__(16) u16  g_W1t[(size_t)NH * INF];       // W1 transposed: (n,k)
__device__ __align__(16) u16  g_W2t[(size_t)OUTF * NH];      // W2 transposed: (o,k)
__device__ __align__(16) u16  g_Hb[(size_t)BATCH * NH];      // H' = mix*relu(h), bf16
__device__ __align__(16) float g_mix[(size_t)BATCH * NLEAF];
__device__ __align__(16) float g_part[(size_t)ZSPL * BATCH * OUTF];  // GEMM2 partials

__device__ inline u16 f2b(float f) {
  __hip_bfloat16 h = __float2bfloat16(f);
  return *reinterpret_cast<u16*>(&h);
}

// Direct global->LDS DMA, 16 B per lane; LDS dest = wave-uniform base + lane*16.
__device__ inline void async16(const u16* g, u16* l) {
  __builtin_amdgcn_global_load_lds((const __attribute__((address_space(1))) void*)g,
                                   (__attribute__((address_space(3))) void*)l, 16, 0, 0);
}

// ------------- batched transpose + cast: dst[b][c][r] = src[b][r][c] -------------
__global__ __launch_bounds__(256) void transpose_cast_kernel(const float* __restrict__ src,
                                                             int which, int R, int C) {
  __shared__ float tile[64 * 65];
  u16* dstbase = which ? g_W2t : g_W1t;
  const float* sb = src + (size_t)blockIdx.z * R * C;
  u16* db = dstbase + (size_t)blockIdx.z * R * C;
  int r0 = blockIdx.y * 64, c0 = blockIdx.x * 64;
  int t = threadIdx.x;
  int cc4 = (t & 15) * 4;
#pragma unroll
  for (int it = 0; it < 4; ++it) {
    int rr = (t >> 4) + it * 16;
    float4 v = *(const float4*)(sb + (size_t)(r0 + rr) * C + c0 + cc4);
    tile[rr * 65 + cc4 + 0] = v.x;
    tile[rr * 65 + cc4 + 1] = v.y;
    tile[rr * 65 + cc4 + 2] = v.z;
    tile[rr * 65 + cc4 + 3] = v.w;
  }
  __syncthreads();
  int cc = t >> 2, rch = (t & 3) * 16;
  u16x8 o0, o1;
#pragma unroll
  for (int j = 0; j < 8; ++j) o0[j] = f2b(tile[(rch + j) * 65 + cc]);
#pragma unroll
  for (int j = 0; j < 8; ++j) o1[j] = f2b(tile[(rch + 8 + j) * 65 + cc]);
  u16* p = db + (size_t)(c0 + cc) * R + r0 + rch;
  *(u16x8*)p = o0;
  *(u16x8*)(p + 8) = o1;
}

// ------------- fused: x->bf16 cast + logits (register-resident) + sigmoid
//               + tree product -> g_mix + out := mix @ b2s seed -------------
// Block = 4 waves; wave handles 2 batch rows held entirely in VGPRs.
// Lane i owns x elements {c*256 + i*4 .. +3 : c=0..3} -> both x and nw loads
// are float4-coalesced. Per node: 32 FMA + 6-step shfl_xor butterfly; lane n
// keeps node n's logits (cndmask), sigmoids computed in parallel at the end.
__global__ __launch_bounds__(256) void mixture_fused_kernel(
    const float* __restrict__ x, const float* __restrict__ nw,
    const float* __restrict__ nb, const float* __restrict__ b2,
    float* __restrict__ out) {
  __shared__ float sig[8][64];
  __shared__ float smix[8][64];
  const int t = threadIdx.x;
  const int wv = t >> 6, ln = t & 63;
  const int b0 = blockIdx.x * 8;
  const int r0 = b0 + wv * 2;  // this wave's first row

  // load 2 rows of x into registers + emit bf16 cast
  float4 xv[2][4];
#pragma unroll
  for (int r = 0; r < 2; ++r)
#pragma unroll
    for (int c = 0; c < 4; ++c) {
      xv[r][c] = *(const float4*)(x + (size_t)(r0 + r) * INF + c * 256 + ln * 4);
      u16x4 pk;
      pk[0] = f2b(xv[r][c].x); pk[1] = f2b(xv[r][c].y);
      pk[2] = f2b(xv[r][c].z); pk[3] = f2b(xv[r][c].w);
      *(u16x4*)(g_Xb + (size_t)(r0 + r) * INF + c * 256 + ln * 4) = pk;
    }

  // 63 node dots
  float keep0 = 0.f, keep1 = 0.f;
  for (int n = 0; n < 63; ++n) {
    float s0 = 0.f, s1 = 0.f;
#pragma unroll
    for (int c = 0; c < 4; ++c) {
      float4 w = *(const float4*)(nw + (size_t)n * INF + c * 256 + ln * 4);
      s0 += w.x * xv[0][c].x + w.y * xv[0][c].y + w.z * xv[0][c].z + w.w * xv[0][c].w;
      s1 += w.x * xv[1][c].x + w.y * xv[1][c].y + w.z * xv[1][c].z + w.w * xv[1][c].w;
    }
#pragma unroll
    for (int off = 1; off < 64; off <<= 1) {
      s0 += __shfl_xor(s0, off);
      s1 += __shfl_xor(s1, off);
    }
    if (ln == n) { keep0 = s0; keep1 = s1; }
  }
  if (ln < 63) {
    float bias = nb[ln];
    sig[wv * 2 + 0][ln] = 1.f / (1.f + __expf(-(keep0 + bias)));
    sig[wv * 2 + 1][ln] = 1.f / (1.f + __expf(-(keep1 + bias)));
  }
  __syncthreads();

  // tree product -> mix
#pragma unroll
  for (int rp = 0; rp < 2; ++rp) {
    int idx = rp * 256 + t;
    int row = idx >> 6, leaf = idx & 63;
    float p = 1.f;
#pragma unroll
    for (int d = 0; d < FDEPTH; ++d) {
      int node = (1 << d) - 1 + (leaf >> (FDEPTH - d));
      int bit = (leaf >> (FDEPTH - 1 - d)) & 1;
      float s = sig[row][node];
      p *= bit ? s : (1.f - s);
    }
    smix[row][leaf] = p;
    g_mix[(size_t)(b0 + row) * 64 + leaf] = p;
  }
  __syncthreads();

  // out seed = mix @ b2s  (cols t and t+256)
  float acc[8][2] = {};
  for (int l = 0; l < 64; ++l) {
    float bv0 = b2[(size_t)l * 512 + t];
    float bv1 = b2[(size_t)l * 512 + t + 256];
#pragma unroll
    for (int r = 0; r < 8; ++r) {
      float m = smix[r][l];
      acc[r][0] += m * bv0;
      acc[r][1] += m * bv1;
    }
  }
#pragma unroll
  for (int r = 0; r < 8; ++r) {
    out[(size_t)(b0 + r) * 512 + t] = acc[r][0];
    out[(size_t)(b0 + r) * 512 + t + 256] = acc[r][1];
  }
}

// ------------- MFMA GEMM, weight-first (C: 4 consecutive out-cols / thread) -------------
// MODE 1: H'(b,n) = mix * relu(Xb @ W1t^T + b1) -> u16x4 direct stores.
// MODE 2: part[z](b,o) = Hb @ W2t^T  (split-K partials, f32x4 stores).
template <int MODE>
__global__ __launch_bounds__(256) void gemm_kernel(const float* __restrict__ b1) {
  constexpr int BM = 128, BN = 128, BK = 64;
  constexpr int K = (MODE == 1) ? 1024 : 4096;
  constexpr int LD = K;
  constexpr int KSPLIT = (MODE == 1) ? 1 : ZSPL;

  __shared__ u16 lsA[BM * BK];  // batch rows (second operand)
  __shared__ u16 lsB[BN * BK];  // weight rows (first operand)

  const u16* __restrict__ A = (MODE == 1) ? g_Xb : g_Hb;
  const u16* __restrict__ Bm = (MODE == 1) ? g_W1t : g_W2t;

  const int t = threadIdx.x;
  const int wv = t >> 6, ln = t & 63;
  const int wm = wv >> 1, wn = wv & 1;  // wm: batch half, wn: col half
  const int quad = ln >> 4, m16 = ln & 15;
  const int am0 = blockIdx.y * BM;
  const int bn0 = blockIdx.x * BN;
  const int kbeg = blockIdx.z * (K / KSPLIT);
  const int kend = kbeg + K / KSPLIT;

  f32x4 acc[4][4] = {};  // [tw: col tile][tb: batch tile]

  for (int kc = kbeg; kc < kend; kc += BK) {
#pragma unroll
    for (int i = 0; i < 4; ++i) {
      int id = i * 256 + t;
      int row = id >> 3;
      int c8 = (id & 7) ^ (row & 7);
      async16(A + (size_t)(am0 + row) * LD + kc + c8 * 8, lsA + (i * 256 + wv * 64) * 8);
    }
#pragma unroll
    for (int i = 0; i < 4; ++i) {
      int id = i * 256 + t;
      int row = id >> 3;
      int c8 = (id & 7) ^ (row & 7);
      async16(Bm + (size_t)(bn0 + row) * LD + kc + c8 * 8, lsB + (i * 256 + wv * 64) * 8);
    }
    __syncthreads();
#pragma unroll
    for (int ks = 0; ks < 2; ++ks) {
      bf16x8 wF[4], xF[4];
#pragma unroll
      for (int tw = 0; tw < 4; ++tw) {
        int row = wn * 64 + tw * 16 + m16;
        wF[tw] = *(const bf16x8*)(lsB + row * BK + ((ks * 4 + quad) ^ (row & 7)) * 8);
      }
#pragma unroll
      for (int tb = 0; tb < 4; ++tb) {
        int row = wm * 64 + tb * 16 + m16;
        xF[tb] = *(const bf16x8*)(lsA + row * BK + ((ks * 4 + quad) ^ (row & 7)) * 8);
      }
#pragma unroll
      for (int tw = 0; tw < 4; ++tw)
#pragma unroll
        for (int tb = 0; tb < 4; ++tb)
          acc[tw][tb] = __builtin_amdgcn_mfma_f32_16x16x32_bf16(wF[tw], xF[tb], acc[tw][tb], 0, 0, 0);
    }
    __syncthreads();
  }

  if (MODE == 1) {
    const int leaf = (bn0 >> 6) + wn;
    float mix4[4];
#pragma unroll
    for (int tb = 0; tb < 4; ++tb) {
      int bg = am0 + wm * 64 + tb * 16 + m16;
      mix4[tb] = g_mix[(size_t)bg * 64 + leaf];
    }
#pragma unroll
    for (int tw = 0; tw < 4; ++tw) {
      int n0g = bn0 + wn * 64 + tw * 16 + quad * 4;
      float4 b1v = *(const float4*)(b1 + n0g);
#pragma unroll
      for (int tb = 0; tb < 4; ++tb) {
        int bg = am0 + wm * 64 + tb * 16 + m16;
        f32x4 a = acc[tw][tb];
        u16x4 pk;
        pk[0] = f2b(fmaxf(a[0] + b1v.x, 0.f) * mix4[tb]);
        pk[1] = f2b(fmaxf(a[1] + b1v.y, 0.f) * mix4[tb]);
        pk[2] = f2b(fmaxf(a[2] + b1v.z, 0.f) * mix4[tb]);
        pk[3] = f2b(fmaxf(a[3] + b1v.w, 0.f) * mix4[tb]);
        *(u16x4*)(g_Hb + (size_t)bg * NH + n0g) = pk;
      }
    }
  } else {
    float* part = g_part + (size_t)blockIdx.z * ((size_t)BATCH * OUTF);
#pragma unroll
    for (int tw = 0; tw < 4; ++tw) {
      int og = bn0 + wn * 64 + tw * 16 + quad * 4;
#pragma unroll
      for (int tb = 0; tb < 4; ++tb) {
        int bg = am0 + wm * 64 + tb * 16 + m16;
        *(f32x4*)(part + (size_t)bg * OUTF + og) = acc[tw][tb];
      }
    }
  }
}

// ------------- out += sum_z part[z] -------------
__global__ __launch_bounds__(256) void reduce_kernel(float* __restrict__ out) {
  int i = (blockIdx.x * 256 + threadIdx.x) * 4;
  float4 s = *(const float4*)(out + i);  // seed = mix @ b2s
#pragma unroll
  for (int z = 0; z < ZSPL; ++z) {
    const float4 p = *(const float4*)(g_part + (size_t)z * BATCH * OUTF + i);
    s.x += p.x; s.y += p.y; s.z += p.z; s.w += p.w;
  }
  *(float4*)(out + i) = s;
}

extern "C" void kernel_launch(void* const* d_in, const int* in_sizes, int n_in,
                              void* d_out, int out_size, void* d_ws, size_t ws_size,
                              hipStream_t stream) {
  const float* x = (const float*)d_in[0];
  const float* nw = (const float*)d_in[1];
  const float* nb = (const float*)d_in[2];
  const float* w1s = (const float*)d_in[3];
  const float* b1s = (const float*)d_in[4];
  const float* w2s = (const float*)d_in[5];
  const float* b2s = (const float*)d_in[6];
  float* out = (float*)d_out;
  (void)d_ws; (void)ws_size;

  hipLaunchKernelGGL(transpose_cast_kernel, dim3(1, 16, 64), dim3(256), 0, stream,
                     w1s, 0, 1024, 64);
  hipLaunchKernelGGL(transpose_cast_kernel, dim3(8, 64, 1), dim3(256), 0, stream,
                     w2s, 1, 4096, 512);
  hipLaunchKernelGGL(mixture_fused_kernel, dim3(512), dim3(256), 0, stream,
                     x, nw, nb, b2s, out);
  hipLaunchKernelGGL(gemm_kernel<1>, dim3(32, 32, 1), dim3(256), 0, stream, b1s);
  hipLaunchKernelGGL(gemm_kernel<2>, dim3(4, 32, ZSPL), dim3(256), 0, stream, b1s);
  hipLaunchKernelGGL(reduce_kernel, dim3(2048), dim3(256), 0, stream, out);
}

// Round 6
// 250.464 us; speedup vs baseline: 1.3598x; 1.3598x over previous
//
#include <hip/hip_runtime.h>
#include <hip/hip_bf16.h>

typedef unsigned short u16;
typedef __attribute__((ext_vector_type(8))) short bf16x8;
typedef __attribute__((ext_vector_type(4))) float f32x4;
typedef __attribute__((ext_vector_type(4))) unsigned short u16x4;
typedef __attribute__((ext_vector_type(8))) unsigned short u16x8;

#define BATCH 4096
#define INF   1024
#define NH    4096   // 64 leaves * 64 hidden
#define OUTF  512
#define NLEAF 64
#define FDEPTH 6
#define ZSPL  8      // GEMM2 split-K ways

// Scratch as device globals (fully rewritten every call; no ws_size dependency).
__device__ __align__(16) u16  g_Xb[(size_t)BATCH * INF];     // x hi, bf16 (b,k)
__device__ __align__(16) u16  g_Xl[(size_t)BATCH * INF];     // x lo, bf16 (b,k)
__device__ __align__(16) u16  g_W1t[(size_t)NH * INF];       // W1 transposed: (n,k)
__device__ __align__(16) u16  g_W2t[(size_t)OUTF * NH];      // W2 transposed: (o,k)
__device__ __align__(16) u16  g_NWh[(size_t)64 * INF];       // node weights hi (row63=0)
__device__ __align__(16) u16  g_NWl[(size_t)64 * INF];       // node weights lo
__device__ __align__(16) u16  g_B2t[(size_t)OUTF * 64];      // b2s transposed (o,l) bf16
__device__ __align__(16) u16  g_Hb[(size_t)BATCH * NH];      // H' = mix*relu(h), bf16
__device__ __align__(16) float g_mix[(size_t)BATCH * NLEAF];
__device__ __align__(16) float g_part[(size_t)ZSPL * BATCH * OUTF];  // GEMM2 partials

__device__ inline u16 f2b(float f) {
  __hip_bfloat16 h = __float2bfloat16(f);
  return *reinterpret_cast<u16*>(&h);
}
__device__ inline float b2f(u16 u) {
  __hip_bfloat16 h = *reinterpret_cast<__hip_bfloat16*>(&u);
  return __bfloat162float(h);
}

// Direct global->LDS DMA, 16 B per lane; LDS dest = wave-uniform base + lane*16.
__device__ inline void async16(const u16* g, u16* l) {
  __builtin_amdgcn_global_load_lds((const __attribute__((address_space(1))) void*)g,
                                   (__attribute__((address_space(3))) void*)l, 16, 0, 0);
}

// ---------------- cast x -> bf16 hi + lo ----------------
__global__ __launch_bounds__(256) void cast_x_kernel(const float* __restrict__ x) {
  int i = (blockIdx.x * 256 + threadIdx.x) * 8;
  float4 v0 = *(const float4*)(x + i);
  float4 v1 = *(const float4*)(x + i + 4);
  float vs[8] = {v0.x, v0.y, v0.z, v0.w, v1.x, v1.y, v1.z, v1.w};
  u16x8 h, l;
#pragma unroll
  for (int j = 0; j < 8; ++j) {
    u16 hb = f2b(vs[j]);
    h[j] = hb;
    l[j] = f2b(vs[j] - b2f(hb));
  }
  *(u16x8*)(g_Xb + i) = h;
  *(u16x8*)(g_Xl + i) = l;
}

// ---------------- cast node weights -> hi/lo, row 63 zeroed ----------------
__global__ __launch_bounds__(256) void cast_nw_kernel(const float* __restrict__ nw) {
  int idx = (blockIdx.x * 256 + threadIdx.x) * 4;
  int n = idx >> 10;
  float4 v = make_float4(0.f, 0.f, 0.f, 0.f);
  if (n < 63) v = *(const float4*)(nw + idx);
  float vs[4] = {v.x, v.y, v.z, v.w};
  u16x4 h, l;
#pragma unroll
  for (int j = 0; j < 4; ++j) {
    u16 hb = f2b(vs[j]);
    h[j] = hb;
    l[j] = f2b(vs[j] - b2f(hb));
  }
  *(u16x4*)(g_NWh + idx) = h;
  *(u16x4*)(g_NWl + idx) = l;
}

// ------------- batched transpose + cast: dst[b][c][r] = src[b][r][c] -------------
// which==0 -> g_W1t (64 batches, R=1024,C=64); which==1 -> g_W2t (R=4096,C=512);
// which==2 -> g_B2t (R=64,C=512)
__global__ __launch_bounds__(256) void transpose_cast_kernel(const float* __restrict__ src,
                                                             int which, int R, int C) {
  __shared__ float tile[64 * 65];
  u16* dstbase = (which == 0) ? g_W1t : (which == 1) ? g_W2t : g_B2t;
  const float* sb = src + (size_t)blockIdx.z * R * C;
  u16* db = dstbase + (size_t)blockIdx.z * R * C;
  int r0 = blockIdx.y * 64, c0 = blockIdx.x * 64;
  int t = threadIdx.x;
  int cc4 = (t & 15) * 4;
#pragma unroll
  for (int it = 0; it < 4; ++it) {
    int rr = (t >> 4) + it * 16;
    float4 v = *(const float4*)(sb + (size_t)(r0 + rr) * C + c0 + cc4);
    tile[rr * 65 + cc4 + 0] = v.x;
    tile[rr * 65 + cc4 + 1] = v.y;
    tile[rr * 65 + cc4 + 2] = v.z;
    tile[rr * 65 + cc4 + 3] = v.w;
  }
  __syncthreads();
  int cc = t >> 2, rch = (t & 3) * 16;
  u16x8 o0, o1;
#pragma unroll
  for (int j = 0; j < 8; ++j) o0[j] = f2b(tile[(rch + j) * 65 + cc]);
#pragma unroll
  for (int j = 0; j < 8; ++j) o1[j] = f2b(tile[(rch + 8 + j) * 65 + cc]);
  u16* p = db + (size_t)(c0 + cc) * R + r0 + rch;
  *(u16x8*)p = o0;
  *(u16x8*)(p + 8) = o1;
}

// ------------- fused mixture: MFMA logits (hi/lo 3-pass, K split over waves)
//               + sigmoid + tree product -> g_mix + MFMA seed out = mix@b2 -------------
// 256 blocks x 16 batch rows. LDS (57344 B), phase-aliased:
//   [0,40960)      per-wave logit staging: wave w at w*10240: NW 8KB + X 2KB
//   [0,16384)      lred[4][64][16] f32   (after logits; aliases staging)
//   [16384,20480)  ssig[16][64] f32
//   [20480,22528)  smixb[16][64] bf16 (chunk-swizzled)
//   [24576,57344)  b2t stage: 256 o-rows x 64 k bf16 (two rounds)
__global__ __launch_bounds__(256) void mixture_mfma_kernel(
    const float* __restrict__ nb, float* __restrict__ out) {
  __shared__ __align__(16) unsigned char lds[57344];
  const int t = threadIdx.x;
  const int wv = t >> 6, ln = t & 63;
  const int quad = ln >> 4, m16 = ln & 15;
  const int r0 = blockIdx.x * 16;

  u16* stW = (u16*)(lds + wv * 10240);
  u16* stX = (u16*)(lds + wv * 10240 + 8192);
  float* lred = (float*)lds;
  float* ssig = (float*)(lds + 16384);
  u16* smixb = (u16*)(lds + 20480);
  u16* b2l = (u16*)(lds + 24576);

  // ---- logits: acc[node-tile] over this wave's K range ----
  const u16* Xs[3] = {g_Xb, g_Xb, g_Xl};
  const u16* Ws[3] = {g_NWh, g_NWl, g_NWh};
  f32x4 acc[4] = {};
#pragma unroll 1
  for (int p = 0; p < 3; ++p) {
    const u16* __restrict__ Xp = Xs[p];
    const u16* __restrict__ Wp = Ws[p];
#pragma unroll 1
    for (int it = 0; it < 4; ++it) {
      int kc = wv * 256 + it * 64;
#pragma unroll
      for (int j = 0; j < 8; ++j) {
        int id = j * 64 + ln;
        int row = id >> 3, c8 = (id & 7) ^ (row & 7);
        async16(Wp + (size_t)row * INF + kc + c8 * 8, stW + j * 512);
      }
#pragma unroll
      for (int j = 0; j < 2; ++j) {
        int id = j * 64 + ln;
        int row = id >> 3, c8 = (id & 7) ^ (row & 7);
        async16(Xp + (size_t)(r0 + row) * INF + kc + c8 * 8, stX + j * 512);
      }
      __syncthreads();
#pragma unroll
      for (int ks = 0; ks < 2; ++ks) {
        bf16x8 bF = *(const bf16x8*)(stX + m16 * 64 + ((ks * 4 + quad) ^ (m16 & 7)) * 8);
#pragma unroll
        for (int tw = 0; tw < 4; ++tw) {
          int row = tw * 16 + m16;
          bf16x8 aF = *(const bf16x8*)(stW + row * 64 + ((ks * 4 + quad) ^ (row & 7)) * 8);
          acc[tw] = __builtin_amdgcn_mfma_f32_16x16x32_bf16(aF, bF, acc[tw], 0, 0, 0);
        }
      }
      __syncthreads();
    }
  }
  // ---- cross-wave K reduction via LDS ----
#pragma unroll
  for (int tw = 0; tw < 4; ++tw)
#pragma unroll
    for (int r = 0; r < 4; ++r)
      lred[((size_t)wv * 64 + tw * 16 + quad * 4 + r) * 16 + m16] = acc[tw][r];
  __syncthreads();

  // issue b2t round-0 DMA early (o rows 0..255); overlaps sigmoid/tree phase
#pragma unroll
  for (int j = 0; j < 8; ++j) {
    int id = (wv * 8 + j) * 64 + ln;
    int row = id >> 3, c8 = (id & 7) ^ (row & 7);
    async16(g_B2t + (size_t)row * 64 + c8 * 8, b2l + (wv * 8 + j) * 512);
  }

  // ---- sigmoid ----
  {
    int n = t & 63, rg = t >> 6;
#pragma unroll
    for (int rr = 0; rr < 4; ++rr) {
      int row = rg * 4 + rr;
      float s = lred[(0 * 64 + n) * 16 + row] + lred[(1 * 64 + n) * 16 + row] +
                lred[(2 * 64 + n) * 16 + row] + lred[(3 * 64 + n) * 16 + row];
      if (n < 63) s += nb[n];
      ssig[row * 64 + n] = 1.f / (1.f + __expf(-s));
    }
  }
  __syncthreads();
  // ---- tree product -> g_mix + smixb (bf16, swizzled) ----
  {
    int leaf = t & 63, rg = t >> 6;
#pragma unroll
    for (int rr = 0; rr < 4; ++rr) {
      int row = rg * 4 + rr;
      float p = 1.f;
#pragma unroll
      for (int d = 0; d < FDEPTH; ++d) {
        int node = (1 << d) - 1 + (leaf >> (FDEPTH - d));
        int bit = (leaf >> (FDEPTH - 1 - d)) & 1;
        float s = ssig[row * 64 + node];
        p *= bit ? s : (1.f - s);
      }
      g_mix[(size_t)(r0 + row) * 64 + leaf] = p;
      smixb[row * 64 + ((leaf >> 3) ^ (row & 7)) * 8 + (leaf & 7)] = f2b(p);
    }
  }
  __syncthreads();  // smixb ready; also drains b2t round-0 DMA

  // ---- seed: out = smix @ b2t^T via MFMA, two o-rounds of 256 ----
  bf16x8 mixF[2];
#pragma unroll
  for (int ks = 0; ks < 2; ++ks)
    mixF[ks] = *(const bf16x8*)(smixb + m16 * 64 + ((ks * 4 + quad) ^ (m16 & 7)) * 8);
#pragma unroll 1
  for (int s = 0; s < 2; ++s) {
    f32x4 sacc[4] = {};
#pragma unroll
    for (int tile = 0; tile < 4; ++tile) {
#pragma unroll
      for (int ks = 0; ks < 2; ++ks) {
        int lrow = wv * 64 + tile * 16 + m16;
        bf16x8 aF = *(const bf16x8*)(b2l + lrow * 64 + ((ks * 4 + quad) ^ (lrow & 7)) * 8);
        sacc[tile] = __builtin_amdgcn_mfma_f32_16x16x32_bf16(aF, mixF[ks], sacc[tile], 0, 0, 0);
      }
    }
#pragma unroll
    for (int tile = 0; tile < 4; ++tile) {
      int o = s * 256 + wv * 64 + tile * 16 + quad * 4;
      *(f32x4*)(out + (size_t)(r0 + m16) * OUTF + o) = sacc[tile];
    }
    if (s == 0) {
      __syncthreads();  // round-0 reads complete before overwrite
#pragma unroll
      for (int j = 0; j < 8; ++j) {
        int id = (wv * 8 + j) * 64 + ln;
        int row = id >> 3, c8 = (id & 7) ^ (row & 7);
        async16(g_B2t + (size_t)(256 + row) * 64 + c8 * 8, b2l + (wv * 8 + j) * 512);
      }
      __syncthreads();  // drain round-1 DMA
    }
  }
}

// ------------- MFMA GEMM, weight-first (C: 4 consecutive out-cols / thread) -------------
// MODE 1: H'(b,n) = mix * relu(Xb @ W1t^T + b1) -> u16x4 direct stores.
// MODE 2: part[z](b,o) = Hb @ W2t^T  (split-K partials, f32x4 stores).
template <int MODE>
__global__ __launch_bounds__(256) void gemm_kernel(const float* __restrict__ b1) {
  constexpr int BM = 128, BN = 128, BK = 64;
  constexpr int K = (MODE == 1) ? 1024 : 4096;
  constexpr int LD = K;
  constexpr int KSPLIT = (MODE == 1) ? 1 : ZSPL;

  __shared__ u16 lsA[BM * BK];  // batch rows (second operand)
  __shared__ u16 lsB[BN * BK];  // weight rows (first operand)

  const u16* __restrict__ A = (MODE == 1) ? g_Xb : g_Hb;
  const u16* __restrict__ Bm = (MODE == 1) ? g_W1t : g_W2t;

  const int t = threadIdx.x;
  const int wv = t >> 6, ln = t & 63;
  const int wm = wv >> 1, wn = wv & 1;  // wm: batch half, wn: col half
  const int quad = ln >> 4, m16 = ln & 15;
  const int am0 = blockIdx.y * BM;
  const int bn0 = blockIdx.x * BN;
  const int kbeg = blockIdx.z * (K / KSPLIT);
  const int kend = kbeg + K / KSPLIT;

  f32x4 acc[4][4] = {};  // [tw: col tile][tb: batch tile]

  for (int kc = kbeg; kc < kend; kc += BK) {
#pragma unroll
    for (int i = 0; i < 4; ++i) {
      int id = i * 256 + t;
      int row = id >> 3;
      int c8 = (id & 7) ^ (row & 7);
      async16(A + (size_t)(am0 + row) * LD + kc + c8 * 8, lsA + (i * 256 + wv * 64) * 8);
    }
#pragma unroll
    for (int i = 0; i < 4; ++i) {
      int id = i * 256 + t;
      int row = id >> 3;
      int c8 = (id & 7) ^ (row & 7);
      async16(Bm + (size_t)(bn0 + row) * LD + kc + c8 * 8, lsB + (i * 256 + wv * 64) * 8);
    }
    __syncthreads();
#pragma unroll
    for (int ks = 0; ks < 2; ++ks) {
      bf16x8 wF[4], xF[4];
#pragma unroll
      for (int tw = 0; tw < 4; ++tw) {
        int row = wn * 64 + tw * 16 + m16;
        wF[tw] = *(const bf16x8*)(lsB + row * BK + ((ks * 4 + quad) ^ (row & 7)) * 8);
      }
#pragma unroll
      for (int tb = 0; tb < 4; ++tb) {
        int row = wm * 64 + tb * 16 + m16;
        xF[tb] = *(const bf16x8*)(lsA + row * BK + ((ks * 4 + quad) ^ (row & 7)) * 8);
      }
#pragma unroll
      for (int tw = 0; tw < 4; ++tw)
#pragma unroll
        for (int tb = 0; tb < 4; ++tb)
          acc[tw][tb] = __builtin_amdgcn_mfma_f32_16x16x32_bf16(wF[tw], xF[tb], acc[tw][tb], 0, 0, 0);
    }
    __syncthreads();
  }

  if (MODE == 1) {
    const int leaf = (bn0 >> 6) + wn;
    float mix4[4];
#pragma unroll
    for (int tb = 0; tb < 4; ++tb) {
      int bg = am0 + wm * 64 + tb * 16 + m16;
      mix4[tb] = g_mix[(size_t)bg * 64 + leaf];
    }
#pragma unroll
    for (int tw = 0; tw < 4; ++tw) {
      int n0g = bn0 + wn * 64 + tw * 16 + quad * 4;
      float4 b1v = *(const float4*)(b1 + n0g);
#pragma unroll
      for (int tb = 0; tb < 4; ++tb) {
        int bg = am0 + wm * 64 + tb * 16 + m16;
        f32x4 a = acc[tw][tb];
        u16x4 pk;
        pk[0] = f2b(fmaxf(a[0] + b1v.x, 0.f) * mix4[tb]);
        pk[1] = f2b(fmaxf(a[1] + b1v.y, 0.f) * mix4[tb]);
        pk[2] = f2b(fmaxf(a[2] + b1v.z, 0.f) * mix4[tb]);
        pk[3] = f2b(fmaxf(a[3] + b1v.w, 0.f) * mix4[tb]);
        *(u16x4*)(g_Hb + (size_t)bg * NH + n0g) = pk;
      }
    }
  } else {
    float* part = g_part + (size_t)blockIdx.z * ((size_t)BATCH * OUTF);
#pragma unroll
    for (int tw = 0; tw < 4; ++tw) {
      int og = bn0 + wn * 64 + tw * 16 + quad * 4;
#pragma unroll
      for (int tb = 0; tb < 4; ++tb) {
        int bg = am0 + wm * 64 + tb * 16 + m16;
        *(f32x4*)(part + (size_t)bg * OUTF + og) = acc[tw][tb];
      }
    }
  }
}

// ------------- out += sum_z part[z] -------------
__global__ __launch_bounds__(256) void reduce_kernel(float* __restrict__ out) {
  int i = (blockIdx.x * 256 + threadIdx.x) * 4;
  float4 s = *(const float4*)(out + i);  // seed = mix @ b2s
#pragma unroll
  for (int z = 0; z < ZSPL; ++z) {
    const float4 p = *(const float4*)(g_part + (size_t)z * BATCH * OUTF + i);
    s.x += p.x; s.y += p.y; s.z += p.z; s.w += p.w;
  }
  *(float4*)(out + i) = s;
}

extern "C" void kernel_launch(void* const* d_in, const int* in_sizes, int n_in,
                              void* d_out, int out_size, void* d_ws, size_t ws_size,
                              hipStream_t stream) {
  const float* x = (const float*)d_in[0];
  const float* nw = (const float*)d_in[1];
  const float* nb = (const float*)d_in[2];
  const float* w1s = (const float*)d_in[3];
  const float* b1s = (const float*)d_in[4];
  const float* w2s = (const float*)d_in[5];
  const float* b2s = (const float*)d_in[6];
  float* out = (float*)d_out;
  (void)d_ws; (void)ws_size;

  hipLaunchKernelGGL(cast_x_kernel, dim3(2048), dim3(256), 0, stream, x);
  hipLaunchKernelGGL(cast_nw_kernel, dim3(64), dim3(256), 0, stream, nw);
  hipLaunchKernelGGL(transpose_cast_kernel, dim3(1, 16, 64), dim3(256), 0, stream,
                     w1s, 0, 1024, 64);
  hipLaunchKernelGGL(transpose_cast_kernel, dim3(8, 64, 1), dim3(256), 0, stream,
                     w2s, 1, 4096, 512);
  hipLaunchKernelGGL(transpose_cast_kernel, dim3(8, 1, 1), dim3(256), 0, stream,
                     b2s, 2, 64, 512);
  hipLaunchKernelGGL(mixture_mfma_kernel, dim3(256), dim3(256), 0, stream, nb, out);
  hipLaunchKernelGGL(gemm_kernel<1>, dim3(32, 32, 1), dim3(256), 0, stream, b1s);
  hipLaunchKernelGGL(gemm_kernel<2>, dim3(4, 32, ZSPL), dim3(256), 0, stream, b1s);
  hipLaunchKernelGGL(reduce_kernel, dim3(2048), dim3(256), 0, stream, out);
}

// Round 7
// 244.163 us; speedup vs baseline: 1.3948x; 1.0258x over previous
//
#include <hip/hip_runtime.h>
#include <hip/hip_bf16.h>

typedef unsigned short u16;
typedef __attribute__((ext_vector_type(8))) short bf16x8;
typedef __attribute__((ext_vector_type(4))) float f32x4;
typedef __attribute__((ext_vector_type(4))) unsigned short u16x4;
typedef __attribute__((ext_vector_type(8))) unsigned short u16x8;

#define BATCH 4096
#define INF   1024
#define NH    4096   // 64 leaves * 64 hidden
#define OUTF  512
#define NLEAF 64
#define FDEPTH 6
#define ZSPL  8      // GEMM2 split-K ways

// Scratch as device globals (fully rewritten every call; no ws_size dependency).
__device__ __align__(16) u16  g_Xb[(size_t)BATCH * INF];     // x, bf16 (b,k)
__device__ __align__(16) u16  g_W1t[(size_t)NH * INF];       // W1 transposed: (n,k)
__device__ __align__(16) u16  g_W2t[(size_t)OUTF * NH];      // W2 transposed: (o,k)
__device__ __align__(16) u16  g_NWh[(size_t)64 * INF];       // node weights bf16 (row63=0)
__device__ __align__(16) u16  g_B2t[(size_t)OUTF * 64];      // b2s transposed (o,l) bf16
__device__ __align__(16) u16  g_Hb[(size_t)BATCH * NH];      // H' = mix*relu(h), bf16
__device__ __align__(16) float g_mix[(size_t)BATCH * NLEAF];
__device__ __align__(16) float g_part[(size_t)ZSPL * BATCH * OUTF];  // GEMM2 partials

__device__ inline u16 f2b(float f) {
  __hip_bfloat16 h = __float2bfloat16(f);
  return *reinterpret_cast<u16*>(&h);
}

// Direct global->LDS DMA, 16 B per lane; LDS dest = wave-uniform base + lane*16.
__device__ inline void async16(const u16* g, u16* l) {
  __builtin_amdgcn_global_load_lds((const __attribute__((address_space(1))) void*)g,
                                   (__attribute__((address_space(3))) void*)l, 16, 0, 0);
}

// ------------- merged prep: casts + transposes, section-decoded -------------
// blocks [0,2048): cast x -> g_Xb (bf16)
// blocks [2048,2112): cast nw -> g_NWh (row 63 zeroed)
// blocks [2112,3136): w1s transpose-cast -> g_W1t (64 batches of 1024x64)
// blocks [3136,3648): w2s transpose-cast -> g_W2t (4096x512)
// blocks [3648,3656): b2s transpose-cast -> g_B2t (64x512)
__global__ __launch_bounds__(256) void prep_kernel(
    const float* __restrict__ x, const float* __restrict__ nw,
    const float* __restrict__ w1s, const float* __restrict__ w2s,
    const float* __restrict__ b2s) {
  __shared__ float tile[64 * 65];
  const int b = blockIdx.x;
  const int t = threadIdx.x;

  if (b < 2048) {  // ---- cast x ----
    int i = (b * 256 + t) * 8;
    float4 v0 = *(const float4*)(x + i);
    float4 v1 = *(const float4*)(x + i + 4);
    u16x8 h;
    h[0] = f2b(v0.x); h[1] = f2b(v0.y); h[2] = f2b(v0.z); h[3] = f2b(v0.w);
    h[4] = f2b(v1.x); h[5] = f2b(v1.y); h[6] = f2b(v1.z); h[7] = f2b(v1.w);
    *(u16x8*)(g_Xb + i) = h;
    return;
  }
  if (b < 2112) {  // ---- cast nw ----
    int idx = ((b - 2048) * 256 + t) * 4;
    int n = idx >> 10;
    float4 v = make_float4(0.f, 0.f, 0.f, 0.f);
    if (n < 63) v = *(const float4*)(nw + idx);
    u16x4 h;
    h[0] = f2b(v.x); h[1] = f2b(v.y); h[2] = f2b(v.z); h[3] = f2b(v.w);
    *(u16x4*)(g_NWh + idx) = h;
    return;
  }

  // ---- transpose-cast sections: dst[c][r] = src[r][c] per 64x64 tile ----
  const float* sb;
  u16* db;
  int R, C, r0, c0;
  if (b < 3136) {
    int idx = b - 2112;
    int z = idx >> 4;
    R = 1024; C = 64;
    r0 = (idx & 15) * 64; c0 = 0;
    sb = w1s + (size_t)z * R * C;
    db = g_W1t + (size_t)z * R * C;
  } else if (b < 3648) {
    int idx = b - 3136;
    R = 4096; C = 512;
    r0 = (idx >> 3) * 64; c0 = (idx & 7) * 64;
    sb = w2s;
    db = g_W2t;
  } else {
    int idx = b - 3648;
    R = 64; C = 512;
    r0 = 0; c0 = idx * 64;
    sb = b2s;
    db = g_B2t;
  }
  int cc4 = (t & 15) * 4;
#pragma unroll
  for (int it = 0; it < 4; ++it) {
    int rr = (t >> 4) + it * 16;
    float4 v = *(const float4*)(sb + (size_t)(r0 + rr) * C + c0 + cc4);
    tile[rr * 65 + cc4 + 0] = v.x;
    tile[rr * 65 + cc4 + 1] = v.y;
    tile[rr * 65 + cc4 + 2] = v.z;
    tile[rr * 65 + cc4 + 3] = v.w;
  }
  __syncthreads();
  int cc = t >> 2, rch = (t & 3) * 16;
  u16x8 o0, o1;
#pragma unroll
  for (int j = 0; j < 8; ++j) o0[j] = f2b(tile[(rch + j) * 65 + cc]);
#pragma unroll
  for (int j = 0; j < 8; ++j) o1[j] = f2b(tile[(rch + 8 + j) * 65 + cc]);
  u16* p = db + (size_t)(c0 + cc) * R + r0 + rch;
  *(u16x8*)p = o0;
  *(u16x8*)(p + 8) = o1;
}

// ------------- fused mixture: MFMA logits (bf16, K split over waves)
//               + sigmoid + tree product -> g_mix + MFMA seed out = mix@b2 -------------
// 256 blocks x 16 batch rows. LDS (57344 B), phase-aliased:
//   [0,40960)      per-wave logit staging: wave w at w*10240: NW 8KB + X 2KB
//   [0,16384)      lred[4][64][16] f32   (after logits; aliases staging)
//   [16384,20480)  ssig[16][64] f32
//   [20480,22528)  smixb[16][64] bf16 (chunk-swizzled)
//   [24576,57344)  b2t stage: 256 o-rows x 64 k bf16 (two rounds)
__global__ __launch_bounds__(256) void mixture_kernel(
    const float* __restrict__ nb, float* __restrict__ out) {
  __shared__ __align__(16) unsigned char lds[57344];
  const int t = threadIdx.x;
  const int wv = t >> 6, ln = t & 63;
  const int quad = ln >> 4, m16 = ln & 15;
  const int r0 = blockIdx.x * 16;

  u16* stW = (u16*)(lds + wv * 10240);
  u16* stX = (u16*)(lds + wv * 10240 + 8192);
  float* lred = (float*)lds;
  float* ssig = (float*)(lds + 16384);
  u16* smixb = (u16*)(lds + 20480);
  u16* b2l = (u16*)(lds + 24576);

  // ---- logits: acc[node-tile] over this wave's K range ----
  f32x4 acc[4] = {};
#pragma unroll 1
  for (int it = 0; it < 4; ++it) {
    int kc = wv * 256 + it * 64;
#pragma unroll
    for (int j = 0; j < 8; ++j) {
      int id = j * 64 + ln;
      int row = id >> 3, c8 = (id & 7) ^ (row & 7);
      async16(g_NWh + (size_t)row * INF + kc + c8 * 8, stW + j * 512);
    }
#pragma unroll
    for (int j = 0; j < 2; ++j) {
      int id = j * 64 + ln;
      int row = id >> 3, c8 = (id & 7) ^ (row & 7);
      async16(g_Xb + (size_t)(r0 + row) * INF + kc + c8 * 8, stX + j * 512);
    }
    __syncthreads();
#pragma unroll
    for (int ks = 0; ks < 2; ++ks) {
      bf16x8 bF = *(const bf16x8*)(stX + m16 * 64 + ((ks * 4 + quad) ^ (m16 & 7)) * 8);
#pragma unroll
      for (int tw = 0; tw < 4; ++tw) {
        int row = tw * 16 + m16;
        bf16x8 aF = *(const bf16x8*)(stW + row * 64 + ((ks * 4 + quad) ^ (row & 7)) * 8);
        acc[tw] = __builtin_amdgcn_mfma_f32_16x16x32_bf16(aF, bF, acc[tw], 0, 0, 0);
      }
    }
    __syncthreads();
  }
  // ---- cross-wave K reduction via LDS ----
#pragma unroll
  for (int tw = 0; tw < 4; ++tw)
#pragma unroll
    for (int r = 0; r < 4; ++r)
      lred[((size_t)wv * 64 + tw * 16 + quad * 4 + r) * 16 + m16] = acc[tw][r];
  __syncthreads();

  // issue b2t round-0 DMA early (o rows 0..255); overlaps sigmoid/tree phase
#pragma unroll
  for (int j = 0; j < 8; ++j) {
    int id = (wv * 8 + j) * 64 + ln;
    int row = id >> 3, c8 = (id & 7) ^ (row & 7);
    async16(g_B2t + (size_t)row * 64 + c8 * 8, b2l + (wv * 8 + j) * 512);
  }

  // ---- sigmoid ----
  {
    int n = t & 63, rg = t >> 6;
#pragma unroll
    for (int rr = 0; rr < 4; ++rr) {
      int row = rg * 4 + rr;
      float s = lred[(0 * 64 + n) * 16 + row] + lred[(1 * 64 + n) * 16 + row] +
                lred[(2 * 64 + n) * 16 + row] + lred[(3 * 64 + n) * 16 + row];
      if (n < 63) s += nb[n];
      ssig[row * 64 + n] = 1.f / (1.f + __expf(-s));
    }
  }
  __syncthreads();
  // ---- tree product -> g_mix + smixb (bf16, swizzled) ----
  {
    int leaf = t & 63, rg = t >> 6;
#pragma unroll
    for (int rr = 0; rr < 4; ++rr) {
      int row = rg * 4 + rr;
      float p = 1.f;
#pragma unroll
      for (int d = 0; d < FDEPTH; ++d) {
        int node = (1 << d) - 1 + (leaf >> (FDEPTH - d));
        int bit = (leaf >> (FDEPTH - 1 - d)) & 1;
        float s = ssig[row * 64 + node];
        p *= bit ? s : (1.f - s);
      }
      g_mix[(size_t)(r0 + row) * 64 + leaf] = p;
      smixb[row * 64 + ((leaf >> 3) ^ (row & 7)) * 8 + (leaf & 7)] = f2b(p);
    }
  }
  __syncthreads();  // smixb ready; also drains b2t round-0 DMA

  // ---- seed: out = smix @ b2t^T via MFMA, two o-rounds of 256 ----
  bf16x8 mixF[2];
#pragma unroll
  for (int ks = 0; ks < 2; ++ks)
    mixF[ks] = *(const bf16x8*)(smixb + m16 * 64 + ((ks * 4 + quad) ^ (m16 & 7)) * 8);
#pragma unroll 1
  for (int s = 0; s < 2; ++s) {
    f32x4 sacc[4] = {};
#pragma unroll
    for (int tile = 0; tile < 4; ++tile) {
#pragma unroll
      for (int ks = 0; ks < 2; ++ks) {
        int lrow = wv * 64 + tile * 16 + m16;
        bf16x8 aF = *(const bf16x8*)(b2l + lrow * 64 + ((ks * 4 + quad) ^ (lrow & 7)) * 8);
        sacc[tile] = __builtin_amdgcn_mfma_f32_16x16x32_bf16(aF, mixF[ks], sacc[tile], 0, 0, 0);
      }
    }
#pragma unroll
    for (int tile = 0; tile < 4; ++tile) {
      int o = s * 256 + wv * 64 + tile * 16 + quad * 4;
      *(f32x4*)(out + (size_t)(r0 + m16) * OUTF + o) = sacc[tile];
    }
    if (s == 0) {
      __syncthreads();  // round-0 reads complete before overwrite
#pragma unroll
      for (int j = 0; j < 8; ++j) {
        int id = (wv * 8 + j) * 64 + ln;
        int row = id >> 3, c8 = (id & 7) ^ (row & 7);
        async16(g_B2t + (size_t)(256 + row) * 64 + c8 * 8, b2l + (wv * 8 + j) * 512);
      }
      __syncthreads();  // drain round-1 DMA
    }
  }
}

// ------------- GEMM1: H'(b,n) = mix * relu(Xb @ W1t^T + b1), u16x4 stores -------------
__global__ __launch_bounds__(256) void gemm1_kernel(const float* __restrict__ b1) {
  constexpr int BM = 128, BN = 128, BK = 64, K = 1024, LD = 1024;

  __shared__ u16 lsA[BM * BK];  // batch rows (second operand)
  __shared__ u16 lsB[BN * BK];  // weight rows (first operand)

  const int t = threadIdx.x;
  const int wv = t >> 6, ln = t & 63;
  const int wm = wv >> 1, wn = wv & 1;
  const int quad = ln >> 4, m16 = ln & 15;
  const int am0 = blockIdx.y * BM;
  const int bn0 = blockIdx.x * BN;

  f32x4 acc[4][4] = {};  // [tw: col tile][tb: batch tile]

  for (int kc = 0; kc < K; kc += BK) {
#pragma unroll
    for (int i = 0; i < 4; ++i) {
      int id = i * 256 + t;
      int row = id >> 3;
      int c8 = (id & 7) ^ (row & 7);
      async16(g_Xb + (size_t)(am0 + row) * LD + kc + c8 * 8, lsA + (i * 256 + wv * 64) * 8);
    }
#pragma unroll
    for (int i = 0; i < 4; ++i) {
      int id = i * 256 + t;
      int row = id >> 3;
      int c8 = (id & 7) ^ (row & 7);
      async16(g_W1t + (size_t)(bn0 + row) * LD + kc + c8 * 8, lsB + (i * 256 + wv * 64) * 8);
    }
    __syncthreads();
#pragma unroll
    for (int ks = 0; ks < 2; ++ks) {
      bf16x8 wF[4], xF[4];
#pragma unroll
      for (int tw = 0; tw < 4; ++tw) {
        int row = wn * 64 + tw * 16 + m16;
        wF[tw] = *(const bf16x8*)(lsB + row * BK + ((ks * 4 + quad) ^ (row & 7)) * 8);
      }
#pragma unroll
      for (int tb = 0; tb < 4; ++tb) {
        int row = wm * 64 + tb * 16 + m16;
        xF[tb] = *(const bf16x8*)(lsA + row * BK + ((ks * 4 + quad) ^ (row & 7)) * 8);
      }
#pragma unroll
      for (int tw = 0; tw < 4; ++tw)
#pragma unroll
        for (int tb = 0; tb < 4; ++tb)
          acc[tw][tb] = __builtin_amdgcn_mfma_f32_16x16x32_bf16(wF[tw], xF[tb], acc[tw][tb], 0, 0, 0);
    }
    __syncthreads();
  }

  const int leaf = (bn0 >> 6) + wn;
  float mix4[4];
#pragma unroll
  for (int tb = 0; tb < 4; ++tb) {
    int bg = am0 + wm * 64 + tb * 16 + m16;
    mix4[tb] = g_mix[(size_t)bg * 64 + leaf];
  }
#pragma unroll
  for (int tw = 0; tw < 4; ++tw) {
    int n0g = bn0 + wn * 64 + tw * 16 + quad * 4;
    float4 b1v = *(const float4*)(b1 + n0g);
#pragma unroll
    for (int tb = 0; tb < 4; ++tb) {
      int bg = am0 + wm * 64 + tb * 16 + m16;
      f32x4 a = acc[tw][tb];
      u16x4 pk;
      pk[0] = f2b(fmaxf(a[0] + b1v.x, 0.f) * mix4[tb]);
      pk[1] = f2b(fmaxf(a[1] + b1v.y, 0.f) * mix4[tb]);
      pk[2] = f2b(fmaxf(a[2] + b1v.z, 0.f) * mix4[tb]);
      pk[3] = f2b(fmaxf(a[3] + b1v.w, 0.f) * mix4[tb]);
      *(u16x4*)(g_Hb + (size_t)bg * NH + n0g) = pk;
    }
  }
}

// ------------- GEMM2: part[z](b,o) = Hb @ W2t^T (split-K partials) -------------
__global__ __launch_bounds__(256) void gemm2_kernel() {
  constexpr int BM = 128, BN = 128, BK = 64, K = 4096, LD = 4096;

  __shared__ u16 lsA[BM * BK];
  __shared__ u16 lsB[BN * BK];

  const int t = threadIdx.x;
  const int wv = t >> 6, ln = t & 63;
  const int wm = wv >> 1, wn = wv & 1;
  const int quad = ln >> 4, m16 = ln & 15;
  const int am0 = blockIdx.y * BM;
  const int bn0 = blockIdx.x * BN;
  const int kbeg = blockIdx.z * (K / ZSPL);
  const int kend = kbeg + K / ZSPL;

  f32x4 acc[4][4] = {};

  for (int kc = kbeg; kc < kend; kc += BK) {
#pragma unroll
    for (int i = 0; i < 4; ++i) {
      int id = i * 256 + t;
      int row = id >> 3;
      int c8 = (id & 7) ^ (row & 7);
      async16(g_Hb + (size_t)(am0 + row) * LD + kc + c8 * 8, lsA + (i * 256 + wv * 64) * 8);
    }
#pragma unroll
    for (int i = 0; i < 4; ++i) {
      int id = i * 256 + t;
      int row = id >> 3;
      int c8 = (id & 7) ^ (row & 7);
      async16(g_W2t + (size_t)(bn0 + row) * LD + kc + c8 * 8, lsB + (i * 256 + wv * 64) * 8);
    }
    __syncthreads();
#pragma unroll
    for (int ks = 0; ks < 2; ++ks) {
      bf16x8 wF[4], xF[4];
#pragma unroll
      for (int tw = 0; tw < 4; ++tw) {
        int row = wn * 64 + tw * 16 + m16;
        wF[tw] = *(const bf16x8*)(lsB + row * BK + ((ks * 4 + quad) ^ (row & 7)) * 8);
      }
#pragma unroll
      for (int tb = 0; tb < 4; ++tb) {
        int row = wm * 64 + tb * 16 + m16;
        xF[tb] = *(const bf16x8*)(lsA + row * BK + ((ks * 4 + quad) ^ (row & 7)) * 8);
      }
#pragma unroll
      for (int tw = 0; tw < 4; ++tw)
#pragma unroll
        for (int tb = 0; tb < 4; ++tb)
          acc[tw][tb] = __builtin_amdgcn_mfma_f32_16x16x32_bf16(wF[tw], xF[tb], acc[tw][tb], 0, 0, 0);
    }
    __syncthreads();
  }

  float* part = g_part + (size_t)blockIdx.z * ((size_t)BATCH * OUTF);
#pragma unroll
  for (int tw = 0; tw < 4; ++tw) {
    int og = bn0 + wn * 64 + tw * 16 + quad * 4;
#pragma unroll
    for (int tb = 0; tb < 4; ++tb) {
      int bg = am0 + wm * 64 + tb * 16 + m16;
      *(f32x4*)(part + (size_t)bg * OUTF + og) = acc[tw][tb];
    }
  }
}

// ------------- out += sum_z part[z] -------------
__global__ __launch_bounds__(256) void reduce_kernel(float* __restrict__ out) {
  int i = (blockIdx.x * 256 + threadIdx.x) * 4;
  float4 s = *(const float4*)(out + i);  // seed = mix @ b2s
#pragma unroll
  for (int z = 0; z < ZSPL; ++z) {
    const float4 p = *(const float4*)(g_part + (size_t)z * BATCH * OUTF + i);
    s.x += p.x; s.y += p.y; s.z += p.z; s.w += p.w;
  }
  *(float4*)(out + i) = s;
}

extern "C" void kernel_launch(void* const* d_in, const int* in_sizes, int n_in,
                              void* d_out, int out_size, void* d_ws, size_t ws_size,
                              hipStream_t stream) {
  const float* x = (const float*)d_in[0];
  const float* nw = (const float*)d_in[1];
  const float* nb = (const float*)d_in[2];
  const float* w1s = (const float*)d_in[3];
  const float* b1s = (const float*)d_in[4];
  const float* w2s = (const float*)d_in[5];
  const float* b2s = (const float*)d_in[6];
  float* out = (float*)d_out;
  (void)d_ws; (void)ws_size;

  hipLaunchKernelGGL(prep_kernel, dim3(3656), dim3(256), 0, stream,
                     x, nw, w1s, w2s, b2s);
  hipLaunchKernelGGL(mixture_kernel, dim3(256), dim3(256), 0, stream, nb, out);
  hipLaunchKernelGGL(gemm1_kernel, dim3(32, 32, 1), dim3(256), 0, stream, b1s);
  hipLaunchKernelGGL(gemm2_kernel, dim3(4, 32, ZSPL), dim3(256), 0, stream);
  hipLaunchKernelGGL(reduce_kernel, dim3(2048), dim3(256), 0, stream, out);
}

// Round 8
// 206.142 us; speedup vs baseline: 1.6521x; 1.1844x over previous
//
#include <hip/hip_runtime.h>
#include <hip/hip_bf16.h>

typedef unsigned short u16;
typedef __attribute__((ext_vector_type(8))) short bf16x8;
typedef __attribute__((ext_vector_type(4))) float f32x4;
typedef __attribute__((ext_vector_type(4))) unsigned short u16x4;
typedef __attribute__((ext_vector_type(8))) unsigned short u16x8;

#define BATCH 4096
#define INF   1024
#define NH    4096   // 64 leaves * 64 hidden
#define OUTF  512
#define NLEAF 64
#define FDEPTH 6
#define ZSPL  4      // GEMM2 split-K ways

// Scratch as device globals (fully rewritten every call; no ws_size dependency).
__device__ __align__(16) u16  g_Xb[(size_t)BATCH * INF];     // x, bf16 (b,k)
__device__ __align__(16) u16  g_W1t[(size_t)NH * INF];       // W1 transposed: (n,k)
__device__ __align__(16) u16  g_W2t[(size_t)OUTF * NH];      // W2 transposed: (o,k)
__device__ __align__(16) u16  g_NWh[(size_t)64 * INF];       // node weights bf16 (row63=0)
__device__ __align__(16) u16  g_B2t[(size_t)OUTF * 64];      // b2s transposed (o,l) bf16
__device__ __align__(16) u16  g_Hb[(size_t)BATCH * NH];      // H' = mix*relu(h), bf16
__device__ __align__(16) float g_mix[(size_t)BATCH * NLEAF];
__device__ __align__(16) float g_part[(size_t)ZSPL * BATCH * OUTF];  // GEMM2 partials

__device__ inline u16 f2b(float f) {
  __hip_bfloat16 h = __float2bfloat16(f);
  return *reinterpret_cast<u16*>(&h);
}

// Direct global->LDS DMA, 16 B per lane; LDS dest = wave-uniform base + lane*16.
__device__ inline void async16(const u16* g, u16* l) {
  __builtin_amdgcn_global_load_lds((const __attribute__((address_space(1))) void*)g,
                                   (__attribute__((address_space(3))) void*)l, 16, 0, 0);
}

// ------------- merged prep: casts + transposes, section-decoded -------------
__global__ __launch_bounds__(256) void prep_kernel(
    const float* __restrict__ x, const float* __restrict__ nw,
    const float* __restrict__ w1s, const float* __restrict__ w2s,
    const float* __restrict__ b2s) {
  __shared__ float tile[64 * 65];
  const int b = blockIdx.x;
  const int t = threadIdx.x;

  if (b < 2048) {  // ---- cast x ----
    int i = (b * 256 + t) * 8;
    float4 v0 = *(const float4*)(x + i);
    float4 v1 = *(const float4*)(x + i + 4);
    u16x8 h;
    h[0] = f2b(v0.x); h[1] = f2b(v0.y); h[2] = f2b(v0.z); h[3] = f2b(v0.w);
    h[4] = f2b(v1.x); h[5] = f2b(v1.y); h[6] = f2b(v1.z); h[7] = f2b(v1.w);
    *(u16x8*)(g_Xb + i) = h;
    return;
  }
  if (b < 2112) {  // ---- cast nw ----
    int idx = ((b - 2048) * 256 + t) * 4;
    int n = idx >> 10;
    float4 v = make_float4(0.f, 0.f, 0.f, 0.f);
    if (n < 63) v = *(const float4*)(nw + idx);
    u16x4 h;
    h[0] = f2b(v.x); h[1] = f2b(v.y); h[2] = f2b(v.z); h[3] = f2b(v.w);
    *(u16x4*)(g_NWh + idx) = h;
    return;
  }

  // ---- transpose-cast sections: dst[c][r] = src[r][c] per 64x64 tile ----
  const float* sb;
  u16* db;
  int R, C, r0, c0;
  if (b < 3136) {
    int idx = b - 2112;
    int z = idx >> 4;
    R = 1024; C = 64;
    r0 = (idx & 15) * 64; c0 = 0;
    sb = w1s + (size_t)z * R * C;
    db = g_W1t + (size_t)z * R * C;
  } else if (b < 3648) {
    int idx = b - 3136;
    R = 4096; C = 512;
    r0 = (idx >> 3) * 64; c0 = (idx & 7) * 64;
    sb = w2s;
    db = g_W2t;
  } else {
    int idx = b - 3648;
    R = 64; C = 512;
    r0 = 0; c0 = idx * 64;
    sb = b2s;
    db = g_B2t;
  }
  int cc4 = (t & 15) * 4;
#pragma unroll
  for (int it = 0; it < 4; ++it) {
    int rr = (t >> 4) + it * 16;
    float4 v = *(const float4*)(sb + (size_t)(r0 + rr) * C + c0 + cc4);
    tile[rr * 65 + cc4 + 0] = v.x;
    tile[rr * 65 + cc4 + 1] = v.y;
    tile[rr * 65 + cc4 + 2] = v.z;
    tile[rr * 65 + cc4 + 3] = v.w;
  }
  __syncthreads();
  int cc = t >> 2, rch = (t & 3) * 16;
  u16x8 o0, o1;
#pragma unroll
  for (int j = 0; j < 8; ++j) o0[j] = f2b(tile[(rch + j) * 65 + cc]);
#pragma unroll
  for (int j = 0; j < 8; ++j) o1[j] = f2b(tile[(rch + 8 + j) * 65 + cc]);
  u16* p = db + (size_t)(c0 + cc) * R + r0 + rch;
  *(u16x8*)p = o0;
  *(u16x8*)(p + 8) = o1;
}

// ------------- fused mixture: MFMA logits + sigmoid + tree product -> g_mix
//               + MFMA seed out = mix@b2 -------------
__global__ __launch_bounds__(256) void mixture_kernel(
    const float* __restrict__ nb, float* __restrict__ out) {
  __shared__ __align__(16) unsigned char lds[57344];
  const int t = threadIdx.x;
  const int wv = t >> 6, ln = t & 63;
  const int quad = ln >> 4, m16 = ln & 15;
  const int r0 = blockIdx.x * 16;

  u16* stW = (u16*)(lds + wv * 10240);
  u16* stX = (u16*)(lds + wv * 10240 + 8192);
  float* lred = (float*)lds;
  float* ssig = (float*)(lds + 16384);
  u16* smixb = (u16*)(lds + 20480);
  u16* b2l = (u16*)(lds + 24576);

  f32x4 acc[4] = {};
#pragma unroll 1
  for (int it = 0; it < 4; ++it) {
    int kc = wv * 256 + it * 64;
#pragma unroll
    for (int j = 0; j < 8; ++j) {
      int id = j * 64 + ln;
      int row = id >> 3, c8 = (id & 7) ^ (row & 7);
      async16(g_NWh + (size_t)row * INF + kc + c8 * 8, stW + j * 512);
    }
#pragma unroll
    for (int j = 0; j < 2; ++j) {
      int id = j * 64 + ln;
      int row = id >> 3, c8 = (id & 7) ^ (row & 7);
      async16(g_Xb + (size_t)(r0 + row) * INF + kc + c8 * 8, stX + j * 512);
    }
    __syncthreads();
#pragma unroll
    for (int ks = 0; ks < 2; ++ks) {
      bf16x8 bF = *(const bf16x8*)(stX + m16 * 64 + ((ks * 4 + quad) ^ (m16 & 7)) * 8);
#pragma unroll
      for (int tw = 0; tw < 4; ++tw) {
        int row = tw * 16 + m16;
        bf16x8 aF = *(const bf16x8*)(stW + row * 64 + ((ks * 4 + quad) ^ (row & 7)) * 8);
        acc[tw] = __builtin_amdgcn_mfma_f32_16x16x32_bf16(aF, bF, acc[tw], 0, 0, 0);
      }
    }
    __syncthreads();
  }
#pragma unroll
  for (int tw = 0; tw < 4; ++tw)
#pragma unroll
    for (int r = 0; r < 4; ++r)
      lred[((size_t)wv * 64 + tw * 16 + quad * 4 + r) * 16 + m16] = acc[tw][r];
  __syncthreads();

#pragma unroll
  for (int j = 0; j < 8; ++j) {
    int id = (wv * 8 + j) * 64 + ln;
    int row = id >> 3, c8 = (id & 7) ^ (row & 7);
    async16(g_B2t + (size_t)row * 64 + c8 * 8, b2l + (wv * 8 + j) * 512);
  }

  {
    int n = t & 63, rg = t >> 6;
#pragma unroll
    for (int rr = 0; rr < 4; ++rr) {
      int row = rg * 4 + rr;
      float s = lred[(0 * 64 + n) * 16 + row] + lred[(1 * 64 + n) * 16 + row] +
                lred[(2 * 64 + n) * 16 + row] + lred[(3 * 64 + n) * 16 + row];
      if (n < 63) s += nb[n];
      ssig[row * 64 + n] = 1.f / (1.f + __expf(-s));
    }
  }
  __syncthreads();
  {
    int leaf = t & 63, rg = t >> 6;
#pragma unroll
    for (int rr = 0; rr < 4; ++rr) {
      int row = rg * 4 + rr;
      float p = 1.f;
#pragma unroll
      for (int d = 0; d < FDEPTH; ++d) {
        int node = (1 << d) - 1 + (leaf >> (FDEPTH - d));
        int bit = (leaf >> (FDEPTH - 1 - d)) & 1;
        float s = ssig[row * 64 + node];
        p *= bit ? s : (1.f - s);
      }
      g_mix[(size_t)(r0 + row) * 64 + leaf] = p;
      smixb[row * 64 + ((leaf >> 3) ^ (row & 7)) * 8 + (leaf & 7)] = f2b(p);
    }
  }
  __syncthreads();

  bf16x8 mixF[2];
#pragma unroll
  for (int ks = 0; ks < 2; ++ks)
    mixF[ks] = *(const bf16x8*)(smixb + m16 * 64 + ((ks * 4 + quad) ^ (m16 & 7)) * 8);
#pragma unroll 1
  for (int s = 0; s < 2; ++s) {
    f32x4 sacc[4] = {};
#pragma unroll
    for (int tile = 0; tile < 4; ++tile) {
#pragma unroll
      for (int ks = 0; ks < 2; ++ks) {
        int lrow = wv * 64 + tile * 16 + m16;
        bf16x8 aF = *(const bf16x8*)(b2l + lrow * 64 + ((ks * 4 + quad) ^ (lrow & 7)) * 8);
        sacc[tile] = __builtin_amdgcn_mfma_f32_16x16x32_bf16(aF, mixF[ks], sacc[tile], 0, 0, 0);
      }
    }
#pragma unroll
    for (int tile = 0; tile < 4; ++tile) {
      int o = s * 256 + wv * 64 + tile * 16 + quad * 4;
      *(f32x4*)(out + (size_t)(r0 + m16) * OUTF + o) = sacc[tile];
    }
    if (s == 0) {
      __syncthreads();
#pragma unroll
      for (int j = 0; j < 8; ++j) {
        int id = (wv * 8 + j) * 64 + ln;
        int row = id >> 3, c8 = (id & 7) ^ (row & 7);
        async16(g_B2t + (size_t)(256 + row) * 64 + c8 * 8, b2l + (wv * 8 + j) * 512);
      }
      __syncthreads();
    }
  }
}

// ------------- GEMM1: H'(b,n) = mix * relu(Xb @ W1t^T + b1) -------------
// Flat 1024-block grid, XCD-swizzled: xcd = bid&7 (8-XCD round-robin dispatch
// assumption); all 32 n-tiles sharing one batch y-tile stay on one XCD so the
// A-tile is fetched into that XCD's L2 once (per-XCD A set = 4x256KB).
__global__ __launch_bounds__(256) void gemm1_kernel(const float* __restrict__ b1) {
  constexpr int BM = 128, BN = 128, BK = 64, K = 1024, LD = 1024;

  __shared__ u16 lsA[BM * BK];
  __shared__ u16 lsB[BN * BK];

  const int bid = blockIdx.x;
  const int xcd = bid & 7, slot = bid >> 3;
  const int ytile = xcd * 4 + (slot >> 5);
  const int xtile = slot & 31;

  const int t = threadIdx.x;
  const int wv = t >> 6, ln = t & 63;
  const int wm = wv >> 1, wn = wv & 1;
  const int quad = ln >> 4, m16 = ln & 15;
  const int am0 = ytile * BM;
  const int bn0 = xtile * BN;

  f32x4 acc[4][4] = {};

  for (int kc = 0; kc < K; kc += BK) {
#pragma unroll
    for (int i = 0; i < 4; ++i) {
      int id = i * 256 + t;
      int row = id >> 3;
      int c8 = (id & 7) ^ (row & 7);
      async16(g_Xb + (size_t)(am0 + row) * LD + kc + c8 * 8, lsA + (i * 256 + wv * 64) * 8);
    }
#pragma unroll
    for (int i = 0; i < 4; ++i) {
      int id = i * 256 + t;
      int row = id >> 3;
      int c8 = (id & 7) ^ (row & 7);
      async16(g_W1t + (size_t)(bn0 + row) * LD + kc + c8 * 8, lsB + (i * 256 + wv * 64) * 8);
    }
    __syncthreads();
#pragma unroll
    for (int ks = 0; ks < 2; ++ks) {
      bf16x8 wF[4], xF[4];
#pragma unroll
      for (int tw = 0; tw < 4; ++tw) {
        int row = wn * 64 + tw * 16 + m16;
        wF[tw] = *(const bf16x8*)(lsB + row * BK + ((ks * 4 + quad) ^ (row & 7)) * 8);
      }
#pragma unroll
      for (int tb = 0; tb < 4; ++tb) {
        int row = wm * 64 + tb * 16 + m16;
        xF[tb] = *(const bf16x8*)(lsA + row * BK + ((ks * 4 + quad) ^ (row & 7)) * 8);
      }
#pragma unroll
      for (int tw = 0; tw < 4; ++tw)
#pragma unroll
        for (int tb = 0; tb < 4; ++tb)
          acc[tw][tb] = __builtin_amdgcn_mfma_f32_16x16x32_bf16(wF[tw], xF[tb], acc[tw][tb], 0, 0, 0);
    }
    __syncthreads();
  }

  const int leaf = (bn0 >> 6) + wn;
  float mix4[4];
#pragma unroll
  for (int tb = 0; tb < 4; ++tb) {
    int bg = am0 + wm * 64 + tb * 16 + m16;
    mix4[tb] = g_mix[(size_t)bg * 64 + leaf];
  }
#pragma unroll
  for (int tw = 0; tw < 4; ++tw) {
    int n0g = bn0 + wn * 64 + tw * 16 + quad * 4;
    float4 b1v = *(const float4*)(b1 + n0g);
#pragma unroll
    for (int tb = 0; tb < 4; ++tb) {
      int bg = am0 + wm * 64 + tb * 16 + m16;
      f32x4 a = acc[tw][tb];
      u16x4 pk;
      pk[0] = f2b(fmaxf(a[0] + b1v.x, 0.f) * mix4[tb]);
      pk[1] = f2b(fmaxf(a[1] + b1v.y, 0.f) * mix4[tb]);
      pk[2] = f2b(fmaxf(a[2] + b1v.z, 0.f) * mix4[tb]);
      pk[3] = f2b(fmaxf(a[3] + b1v.w, 0.f) * mix4[tb]);
      *(u16x4*)(g_Hb + (size_t)bg * NH + n0g) = pk;
    }
  }
}

// ------------- GEMM2: part[z](b,o) = Hb @ W2t^T (split-K partials) -------------
// Flat 512-block grid, XCD-swizzled: per XCD 4 batch y-tiles x (4 o-tiles x
// 4 z) -> A slices stay in one XCD's L2 (4x1MB), fetched from HBM once.
__global__ __launch_bounds__(256) void gemm2_kernel() {
  constexpr int BM = 128, BN = 128, BK = 64, K = 4096, LD = 4096;

  __shared__ u16 lsA[BM * BK];
  __shared__ u16 lsB[BN * BK];

  const int bid = blockIdx.x;
  const int xcd = bid & 7, slot = bid >> 3;        // 64 slots per XCD
  const int ytile = xcd * 4 + (slot >> 4);
  const int rem = slot & 15;
  const int xtile = rem & 3, zidx = rem >> 2;

  const int t = threadIdx.x;
  const int wv = t >> 6, ln = t & 63;
  const int wm = wv >> 1, wn = wv & 1;
  const int quad = ln >> 4, m16 = ln & 15;
  const int am0 = ytile * BM;
  const int bn0 = xtile * BN;
  const int kbeg = zidx * (K / ZSPL);
  const int kend = kbeg + K / ZSPL;

  f32x4 acc[4][4] = {};

  for (int kc = kbeg; kc < kend; kc += BK) {
#pragma unroll
    for (int i = 0; i < 4; ++i) {
      int id = i * 256 + t;
      int row = id >> 3;
      int c8 = (id & 7) ^ (row & 7);
      async16(g_Hb + (size_t)(am0 + row) * LD + kc + c8 * 8, lsA + (i * 256 + wv * 64) * 8);
    }
#pragma unroll
    for (int i = 0; i < 4; ++i) {
      int id = i * 256 + t;
      int row = id >> 3;
      int c8 = (id & 7) ^ (row & 7);
      async16(g_W2t + (size_t)(bn0 + row) * LD + kc + c8 * 8, lsB + (i * 256 + wv * 64) * 8);
    }
    __syncthreads();
#pragma unroll
    for (int ks = 0; ks < 2; ++ks) {
      bf16x8 wF[4], xF[4];
#pragma unroll
      for (int tw = 0; tw < 4; ++tw) {
        int row = wn * 64 + tw * 16 + m16;
        wF[tw] = *(const bf16x8*)(lsB + row * BK + ((ks * 4 + quad) ^ (row & 7)) * 8);
      }
#pragma unroll
      for (int tb = 0; tb < 4; ++tb) {
        int row = wm * 64 + tb * 16 + m16;
        xF[tb] = *(const bf16x8*)(lsA + row * BK + ((ks * 4 + quad) ^ (row & 7)) * 8);
      }
#pragma unroll
      for (int tw = 0; tw < 4; ++tw)
#pragma unroll
        for (int tb = 0; tb < 4; ++tb)
          acc[tw][tb] = __builtin_amdgcn_mfma_f32_16x16x32_bf16(wF[tw], xF[tb], acc[tw][tb], 0, 0, 0);
    }
    __syncthreads();
  }

  float* part = g_part + (size_t)zidx * ((size_t)BATCH * OUTF);
#pragma unroll
  for (int tw = 0; tw < 4; ++tw) {
    int og = bn0 + wn * 64 + tw * 16 + quad * 4;
#pragma unroll
    for (int tb = 0; tb < 4; ++tb) {
      int bg = am0 + wm * 64 + tb * 16 + m16;
      *(f32x4*)(part + (size_t)bg * OUTF + og) = acc[tw][tb];
    }
  }
}

// ------------- out += sum_z part[z] -------------
__global__ __launch_bounds__(256) void reduce_kernel(float* __restrict__ out) {
  int i = (blockIdx.x * 256 + threadIdx.x) * 4;
  float4 s = *(const float4*)(out + i);  // seed = mix @ b2s
#pragma unroll
  for (int z = 0; z < ZSPL; ++z) {
    const float4 p = *(const float4*)(g_part + (size_t)z * BATCH * OUTF + i);
    s.x += p.x; s.y += p.y; s.z += p.z; s.w += p.w;
  }
  *(float4*)(out + i) = s;
}

extern "C" void kernel_launch(void* const* d_in, const int* in_sizes, int n_in,
                              void* d_out, int out_size, void* d_ws, size_t ws_size,
                              hipStream_t stream) {
  const float* x = (const float*)d_in[0];
  const float* nw = (const float*)d_in[1];
  const float* nb = (const float*)d_in[2];
  const float* w1s = (const float*)d_in[3];
  const float* b1s = (const float*)d_in[4];
  const float* w2s = (const float*)d_in[5];
  const float* b2s = (const float*)d_in[6];
  float* out = (float*)d_out;
  (void)d_ws; (void)ws_size;

  hipLaunchKernelGGL(prep_kernel, dim3(3656), dim3(256), 0, stream,
                     x, nw, w1s, w2s, b2s);
  hipLaunchKernelGGL(mixture_kernel, dim3(256), dim3(256), 0, stream, nb, out);
  hipLaunchKernelGGL(gemm1_kernel, dim3(1024), dim3(256), 0, stream, b1s);
  hipLaunchKernelGGL(gemm2_kernel, dim3(512), dim3(256), 0, stream);
  hipLaunchKernelGGL(reduce_kernel, dim3(2048), dim3(256), 0, stream, out);
}

// Round 9
// 203.568 us; speedup vs baseline: 1.6730x; 1.0126x over previous
//
#include <hip/hip_runtime.h>
#include <hip/hip_bf16.h>

typedef unsigned short u16;
typedef __attribute__((ext_vector_type(8))) short bf16x8;
typedef __attribute__((ext_vector_type(4))) float f32x4;
typedef __attribute__((ext_vector_type(16))) float f32x16;
typedef __attribute__((ext_vector_type(4))) unsigned short u16x4;
typedef __attribute__((ext_vector_type(8))) unsigned short u16x8;

#define BATCH 4096
#define INF   1024
#define NH    4096   // 64 leaves * 64 hidden
#define OUTF  512
#define NLEAF 64
#define FDEPTH 6
#define ZSPL  4      // GEMM2 split-K ways

// Scratch as device globals (fully rewritten every call; no ws_size dependency).
__device__ __align__(16) u16  g_Xb[(size_t)BATCH * INF];     // x, bf16 (b,k)
__device__ __align__(16) u16  g_W1t[(size_t)NH * INF];       // W1 transposed: (n,k)
__device__ __align__(16) u16  g_W2t[(size_t)OUTF * NH];      // W2 transposed: (o,k)
__device__ __align__(16) u16  g_NWh[(size_t)64 * INF];       // node weights bf16 (row63=0)
__device__ __align__(16) u16  g_B2t[(size_t)OUTF * 64];      // b2s transposed (o,l) bf16
__device__ __align__(16) u16  g_Hb[(size_t)BATCH * NH];      // H' = mix*relu(h), bf16
__device__ __align__(16) float g_mix[(size_t)BATCH * NLEAF];
__device__ __align__(16) float g_part[(size_t)ZSPL * BATCH * OUTF];  // GEMM2 partials

__device__ inline u16 f2b(float f) {
  __hip_bfloat16 h = __float2bfloat16(f);
  return *reinterpret_cast<u16*>(&h);
}

// Direct global->LDS DMA, 16 B per lane; LDS dest = wave-uniform base + lane*16.
__device__ inline void async16(const u16* g, u16* l) {
  __builtin_amdgcn_global_load_lds((const __attribute__((address_space(1))) void*)g,
                                   (__attribute__((address_space(3))) void*)l, 16, 0, 0);
}

// ------------- merged prep: casts + transposes, section-decoded -------------
__global__ __launch_bounds__(256) void prep_kernel(
    const float* __restrict__ x, const float* __restrict__ nw,
    const float* __restrict__ w1s, const float* __restrict__ w2s,
    const float* __restrict__ b2s) {
  __shared__ float tile[64 * 65];
  const int b = blockIdx.x;
  const int t = threadIdx.x;

  if (b < 2048) {  // ---- cast x ----
    int i = (b * 256 + t) * 8;
    float4 v0 = *(const float4*)(x + i);
    float4 v1 = *(const float4*)(x + i + 4);
    u16x8 h;
    h[0] = f2b(v0.x); h[1] = f2b(v0.y); h[2] = f2b(v0.z); h[3] = f2b(v0.w);
    h[4] = f2b(v1.x); h[5] = f2b(v1.y); h[6] = f2b(v1.z); h[7] = f2b(v1.w);
    *(u16x8*)(g_Xb + i) = h;
    return;
  }
  if (b < 2112) {  // ---- cast nw ----
    int idx = ((b - 2048) * 256 + t) * 4;
    int n = idx >> 10;
    float4 v = make_float4(0.f, 0.f, 0.f, 0.f);
    if (n < 63) v = *(const float4*)(nw + idx);
    u16x4 h;
    h[0] = f2b(v.x); h[1] = f2b(v.y); h[2] = f2b(v.z); h[3] = f2b(v.w);
    *(u16x4*)(g_NWh + idx) = h;
    return;
  }

  // ---- transpose-cast sections: dst[c][r] = src[r][c] per 64x64 tile ----
  const float* sb;
  u16* db;
  int R, C, r0, c0;
  if (b < 3136) {
    int idx = b - 2112;
    int z = idx >> 4;
    R = 1024; C = 64;
    r0 = (idx & 15) * 64; c0 = 0;
    sb = w1s + (size_t)z * R * C;
    db = g_W1t + (size_t)z * R * C;
  } else if (b < 3648) {
    int idx = b - 3136;
    R = 4096; C = 512;
    r0 = (idx >> 3) * 64; c0 = (idx & 7) * 64;
    sb = w2s;
    db = g_W2t;
  } else {
    int idx = b - 3648;
    R = 64; C = 512;
    r0 = 0; c0 = idx * 64;
    sb = b2s;
    db = g_B2t;
  }
  int cc4 = (t & 15) * 4;
#pragma unroll
  for (int it = 0; it < 4; ++it) {
    int rr = (t >> 4) + it * 16;
    float4 v = *(const float4*)(sb + (size_t)(r0 + rr) * C + c0 + cc4);
    tile[rr * 65 + cc4 + 0] = v.x;
    tile[rr * 65 + cc4 + 1] = v.y;
    tile[rr * 65 + cc4 + 2] = v.z;
    tile[rr * 65 + cc4 + 3] = v.w;
  }
  __syncthreads();
  int cc = t >> 2, rch = (t & 3) * 16;
  u16x8 o0, o1;
#pragma unroll
  for (int j = 0; j < 8; ++j) o0[j] = f2b(tile[(rch + j) * 65 + cc]);
#pragma unroll
  for (int j = 0; j < 8; ++j) o1[j] = f2b(tile[(rch + 8 + j) * 65 + cc]);
  u16* p = db + (size_t)(c0 + cc) * R + r0 + rch;
  *(u16x8*)p = o0;
  *(u16x8*)(p + 8) = o1;
}

// ------------- fused mixture: MFMA logits + sigmoid + tree product -> g_mix
//               + MFMA seed out = mix@b2 -------------
__global__ __launch_bounds__(256) void mixture_kernel(
    const float* __restrict__ nb, float* __restrict__ out) {
  __shared__ __align__(16) unsigned char lds[57344];
  const int t = threadIdx.x;
  const int wv = t >> 6, ln = t & 63;
  const int quad = ln >> 4, m16 = ln & 15;
  const int r0 = blockIdx.x * 16;

  u16* stW = (u16*)(lds + wv * 10240);
  u16* stX = (u16*)(lds + wv * 10240 + 8192);
  float* lred = (float*)lds;
  float* ssig = (float*)(lds + 16384);
  u16* smixb = (u16*)(lds + 20480);
  u16* b2l = (u16*)(lds + 24576);

  f32x4 acc[4] = {};
#pragma unroll 1
  for (int it = 0; it < 4; ++it) {
    int kc = wv * 256 + it * 64;
#pragma unroll
    for (int j = 0; j < 8; ++j) {
      int id = j * 64 + ln;
      int row = id >> 3, c8 = (id & 7) ^ (row & 7);
      async16(g_NWh + (size_t)row * INF + kc + c8 * 8, stW + j * 512);
    }
#pragma unroll
    for (int j = 0; j < 2; ++j) {
      int id = j * 64 + ln;
      int row = id >> 3, c8 = (id & 7) ^ (row & 7);
      async16(g_Xb + (size_t)(r0 + row) * INF + kc + c8 * 8, stX + j * 512);
    }
    __syncthreads();
#pragma unroll
    for (int ks = 0; ks < 2; ++ks) {
      bf16x8 bF = *(const bf16x8*)(stX + m16 * 64 + ((ks * 4 + quad) ^ (m16 & 7)) * 8);
#pragma unroll
      for (int tw = 0; tw < 4; ++tw) {
        int row = tw * 16 + m16;
        bf16x8 aF = *(const bf16x8*)(stW + row * 64 + ((ks * 4 + quad) ^ (row & 7)) * 8);
        acc[tw] = __builtin_amdgcn_mfma_f32_16x16x32_bf16(aF, bF, acc[tw], 0, 0, 0);
      }
    }
    __syncthreads();
  }
#pragma unroll
  for (int tw = 0; tw < 4; ++tw)
#pragma unroll
    for (int r = 0; r < 4; ++r)
      lred[((size_t)wv * 64 + tw * 16 + quad * 4 + r) * 16 + m16] = acc[tw][r];
  __syncthreads();

#pragma unroll
  for (int j = 0; j < 8; ++j) {
    int id = (wv * 8 + j) * 64 + ln;
    int row = id >> 3, c8 = (id & 7) ^ (row & 7);
    async16(g_B2t + (size_t)row * 64 + c8 * 8, b2l + (wv * 8 + j) * 512);
  }

  {
    int n = t & 63, rg = t >> 6;
#pragma unroll
    for (int rr = 0; rr < 4; ++rr) {
      int row = rg * 4 + rr;
      float s = lred[(0 * 64 + n) * 16 + row] + lred[(1 * 64 + n) * 16 + row] +
                lred[(2 * 64 + n) * 16 + row] + lred[(3 * 64 + n) * 16 + row];
      if (n < 63) s += nb[n];
      ssig[row * 64 + n] = 1.f / (1.f + __expf(-s));
    }
  }
  __syncthreads();
  {
    int leaf = t & 63, rg = t >> 6;
#pragma unroll
    for (int rr = 0; rr < 4; ++rr) {
      int row = rg * 4 + rr;
      float p = 1.f;
#pragma unroll
      for (int d = 0; d < FDEPTH; ++d) {
        int node = (1 << d) - 1 + (leaf >> (FDEPTH - d));
        int bit = (leaf >> (FDEPTH - 1 - d)) & 1;
        float s = ssig[row * 64 + node];
        p *= bit ? s : (1.f - s);
      }
      g_mix[(size_t)(r0 + row) * 64 + leaf] = p;
      smixb[row * 64 + ((leaf >> 3) ^ (row & 7)) * 8 + (leaf & 7)] = f2b(p);
    }
  }
  __syncthreads();

  bf16x8 mixF[2];
#pragma unroll
  for (int ks = 0; ks < 2; ++ks)
    mixF[ks] = *(const bf16x8*)(smixb + m16 * 64 + ((ks * 4 + quad) ^ (m16 & 7)) * 8);
#pragma unroll 1
  for (int s = 0; s < 2; ++s) {
    f32x4 sacc[4] = {};
#pragma unroll
    for (int tile = 0; tile < 4; ++tile) {
#pragma unroll
      for (int ks = 0; ks < 2; ++ks) {
        int lrow = wv * 64 + tile * 16 + m16;
        bf16x8 aF = *(const bf16x8*)(b2l + lrow * 64 + ((ks * 4 + quad) ^ (lrow & 7)) * 8);
        sacc[tile] = __builtin_amdgcn_mfma_f32_16x16x32_bf16(aF, mixF[ks], sacc[tile], 0, 0, 0);
      }
    }
#pragma unroll
    for (int tile = 0; tile < 4; ++tile) {
      int o = s * 256 + wv * 64 + tile * 16 + quad * 4;
      *(f32x4*)(out + (size_t)(r0 + m16) * OUTF + o) = sacc[tile];
    }
    if (s == 0) {
      __syncthreads();
#pragma unroll
      for (int j = 0; j < 8; ++j) {
        int id = (wv * 8 + j) * 64 + ln;
        int row = id >> 3, c8 = (id & 7) ^ (row & 7);
        async16(g_B2t + (size_t)(256 + row) * 64 + c8 * 8, b2l + (wv * 8 + j) * 512);
      }
      __syncthreads();
    }
  }
}

// ------------- GEMM1: H'(b,n) = mix * relu(Xb @ W1t^T + b1) -------------
// 32x32x16 MFMA (2382 TF ubench vs 2075 for 16x16): same ds_read count per
// BK, half the MFMA issues. C/D layout (m74/m101 verified): col=lane&31,
// row=(reg&3)+8*(reg>>2)+4*(lane>>5). Plain 2-D grid (round-8 XCD swizzle
// refetched all of W1t per XCD: FETCH 47->73 MB -- reverted).
__global__ __launch_bounds__(256) void gemm1_kernel(const float* __restrict__ b1) {
  constexpr int BM = 128, BN = 128, BK = 64, K = 1024, LD = 1024;

  __shared__ u16 lsA[BM * BK];  // batch rows (second operand)
  __shared__ u16 lsB[BN * BK];  // weight rows (first operand)

  const int t = threadIdx.x;
  const int wv = t >> 6, ln = t & 63;
  const int wm = wv >> 1, wn = wv & 1;
  const int l32 = ln & 31, lh = ln >> 5;
  const int am0 = blockIdx.y * BM;
  const int bn0 = blockIdx.x * BN;

  f32x16 acc[2][2] = {};  // [tw: col 32-tile][tb: batch 32-tile]

  for (int kc = 0; kc < K; kc += BK) {
#pragma unroll
    for (int i = 0; i < 4; ++i) {
      int id = i * 256 + t;
      int row = id >> 3;
      int c8 = (id & 7) ^ (row & 7);
      async16(g_Xb + (size_t)(am0 + row) * LD + kc + c8 * 8, lsA + (i * 256 + wv * 64) * 8);
    }
#pragma unroll
    for (int i = 0; i < 4; ++i) {
      int id = i * 256 + t;
      int row = id >> 3;
      int c8 = (id & 7) ^ (row & 7);
      async16(g_W1t + (size_t)(bn0 + row) * LD + kc + c8 * 8, lsB + (i * 256 + wv * 64) * 8);
    }
    __syncthreads();
#pragma unroll
    for (int ks = 0; ks < 4; ++ks) {  // K=16 per step
      bf16x8 wF[2], xF[2];
#pragma unroll
      for (int tw = 0; tw < 2; ++tw) {
        int row = wn * 64 + tw * 32 + l32;
        wF[tw] = *(const bf16x8*)(lsB + row * BK + ((ks * 2 + lh) ^ (row & 7)) * 8);
      }
#pragma unroll
      for (int tb = 0; tb < 2; ++tb) {
        int row = wm * 64 + tb * 32 + l32;
        xF[tb] = *(const bf16x8*)(lsA + row * BK + ((ks * 2 + lh) ^ (row & 7)) * 8);
      }
#pragma unroll
      for (int tw = 0; tw < 2; ++tw)
#pragma unroll
        for (int tb = 0; tb < 2; ++tb)
          acc[tw][tb] = __builtin_amdgcn_mfma_f32_32x32x16_bf16(wF[tw], xF[tb], acc[tw][tb], 0, 0, 0);
    }
    __syncthreads();
  }

  const int leaf = (bn0 >> 6) + wn;
#pragma unroll
  for (int tb = 0; tb < 2; ++tb) {
    int bg = am0 + wm * 64 + tb * 32 + l32;
    float mixv = g_mix[(size_t)bg * 64 + leaf];
#pragma unroll
    for (int tw = 0; tw < 2; ++tw) {
#pragma unroll
      for (int g = 0; g < 4; ++g) {
        int col0 = bn0 + wn * 64 + tw * 32 + g * 8 + lh * 4;
        float4 b1v = *(const float4*)(b1 + col0);
        u16x4 pk;
        pk[0] = f2b(fmaxf(acc[tw][tb][g * 4 + 0] + b1v.x, 0.f) * mixv);
        pk[1] = f2b(fmaxf(acc[tw][tb][g * 4 + 1] + b1v.y, 0.f) * mixv);
        pk[2] = f2b(fmaxf(acc[tw][tb][g * 4 + 2] + b1v.z, 0.f) * mixv);
        pk[3] = f2b(fmaxf(acc[tw][tb][g * 4 + 3] + b1v.w, 0.f) * mixv);
        *(u16x4*)(g_Hb + (size_t)bg * NH + col0) = pk;
      }
    }
  }
}

// ------------- GEMM2: part[z](b,o) = Hb @ W2t^T (split-K partials) -------------
// Flat 512-block grid, XCD-swizzled (round-8: cut FETCH 107->~64 MB).
__global__ __launch_bounds__(256) void gemm2_kernel() {
  constexpr int BM = 128, BN = 128, BK = 64, K = 4096, LD = 4096;

  __shared__ u16 lsA[BM * BK];
  __shared__ u16 lsB[BN * BK];

  const int bid = blockIdx.x;
  const int xcd = bid & 7, slot = bid >> 3;        // 64 slots per XCD
  const int ytile = xcd * 4 + (slot >> 4);
  const int rem = slot & 15;
  const int xtile = rem & 3, zidx = rem >> 2;

  const int t = threadIdx.x;
  const int wv = t >> 6, ln = t & 63;
  const int wm = wv >> 1, wn = wv & 1;
  const int quad = ln >> 4, m16 = ln & 15;
  const int am0 = ytile * BM;
  const int bn0 = xtile * BN;
  const int kbeg = zidx * (K / ZSPL);
  const int kend = kbeg + K / ZSPL;

  f32x4 acc[4][4] = {};

  for (int kc = kbeg; kc < kend; kc += BK) {
#pragma unroll
    for (int i = 0; i < 4; ++i) {
      int id = i * 256 + t;
      int row = id >> 3;
      int c8 = (id & 7) ^ (row & 7);
      async16(g_Hb + (size_t)(am0 + row) * LD + kc + c8 * 8, lsA + (i * 256 + wv * 64) * 8);
    }
#pragma unroll
    for (int i = 0; i < 4; ++i) {
      int id = i * 256 + t;
      int row = id >> 3;
      int c8 = (id & 7) ^ (row & 7);
      async16(g_W2t + (size_t)(bn0 + row) * LD + kc + c8 * 8, lsB + (i * 256 + wv * 64) * 8);
    }
    __syncthreads();
#pragma unroll
    for (int ks = 0; ks < 2; ++ks) {
      bf16x8 wF[4], xF[4];
#pragma unroll
      for (int tw = 0; tw < 4; ++tw) {
        int row = wn * 64 + tw * 16 + m16;
        wF[tw] = *(const bf16x8*)(lsB + row * BK + ((ks * 4 + quad) ^ (row & 7)) * 8);
      }
#pragma unroll
      for (int tb = 0; tb < 4; ++tb) {
        int row = wm * 64 + tb * 16 + m16;
        xF[tb] = *(const bf16x8*)(lsA + row * BK + ((ks * 4 + quad) ^ (row & 7)) * 8);
      }
#pragma unroll
      for (int tw = 0; tw < 4; ++tw)
#pragma unroll
        for (int tb = 0; tb < 4; ++tb)
          acc[tw][tb] = __builtin_amdgcn_mfma_f32_16x16x32_bf16(wF[tw], xF[tb], acc[tw][tb], 0, 0, 0);
    }
    __syncthreads();
  }

  float* part = g_part + (size_t)zidx * ((size_t)BATCH * OUTF);
#pragma unroll
  for (int tw = 0; tw < 4; ++tw) {
    int og = bn0 + wn * 64 + tw * 16 + quad * 4;
#pragma unroll
    for (int tb = 0; tb < 4; ++tb) {
      int bg = am0 + wm * 64 + tb * 16 + m16;
      *(f32x4*)(part + (size_t)bg * OUTF + og) = acc[tw][tb];
    }
  }
}

// ------------- out += sum_z part[z] -------------
__global__ __launch_bounds__(256) void reduce_kernel(float* __restrict__ out) {
  int i = (blockIdx.x * 256 + threadIdx.x) * 4;
  float4 s = *(const float4*)(out + i);  // seed = mix @ b2s
#pragma unroll
  for (int z = 0; z < ZSPL; ++z) {
    const float4 p = *(const float4*)(g_part + (size_t)z * BATCH * OUTF + i);
    s.x += p.x; s.y += p.y; s.z += p.z; s.w += p.w;
  }
  *(float4*)(out + i) = s;
}

extern "C" void kernel_launch(void* const* d_in, const int* in_sizes, int n_in,
                              void* d_out, int out_size, void* d_ws, size_t ws_size,
                              hipStream_t stream) {
  const float* x = (const float*)d_in[0];
  const float* nw = (const float*)d_in[1];
  const float* nb = (const float*)d_in[2];
  const float* w1s = (const float*)d_in[3];
  const float* b1s = (const float*)d_in[4];
  const float* w2s = (const float*)d_in[5];
  const float* b2s = (const float*)d_in[6];
  float* out = (float*)d_out;
  (void)d_ws; (void)ws_size;

  hipLaunchKernelGGL(prep_kernel, dim3(3656), dim3(256), 0, stream,
                     x, nw, w1s, w2s, b2s);
  hipLaunchKernelGGL(mixture_kernel, dim3(256), dim3(256), 0, stream, nb, out);
  hipLaunchKernelGGL(gemm1_kernel, dim3(32, 32), dim3(256), 0, stream, b1s);
  hipLaunchKernelGGL(gemm2_kernel, dim3(512), dim3(256), 0, stream);
  hipLaunchKernelGGL(reduce_kernel, dim3(2048), dim3(256), 0, stream, out);
}